// Round 1
// baseline (1181.926 us; speedup 1.0000x reference)
//
#include <hip/hip_runtime.h>
#include <hip/hip_bf16.h>
#include <cmath>

namespace {
constexpr int B_ = 16, N_ = 307, T_ = 24, C_ = 128, H_ = 8, D_ = 16, S_ = 20, U_ = 20;
constexpr int NROW = B_ * N_ * T_;          // 117888
constexpr int NX = NROW * C_;               // 15089664
constexpr int TEPE_N = B_ * T_ * C_;        // 49152
constexpr int ROWS_PB = 16;                 // rows per block for row-tiled kernels
constexpr int NBLK_ROWS = NROW / ROWS_PB;   // 7368
constexpr int FF = 4 * C_;                  // 512
}

// ---------------- kernel 0: tepe[b,t,c] = pos_emb(t,c) + sum of 5 embedding lookups
__global__ void k_tepe(const int* __restrict__ te,
                       const float* __restrict__ e_min, const float* __restrict__ e_hr,
                       const float* __restrict__ e_wd, const float* __restrict__ e_mo,
                       const float* __restrict__ e_yr, float* __restrict__ tepe) {
    int i = blockIdx.x * blockDim.x + threadIdx.x;
    if (i >= TEPE_N) return;
    int c = i & (C_ - 1);
    int bt = i >> 7;              // b*T + t
    int t = bt % T_;
    const int* enc = te + bt * 5;
    float v = e_min[enc[0] * C_ + c] + e_hr[enc[1] * C_ + c] + e_wd[enc[2] * C_ + c]
            + e_mo[enc[3] * C_ + c] + e_yr[enc[4] * C_ + c];
    float ang = (float)t * expf(-(float)(c & ~1) * (9.210340371976184f / 128.0f));
    v += (c & 1) ? cosf(ang) : sinf(ang);
    tepe[i] = v;
}

// ---------------- kernel 1: QKV projection. x recomputed on the fly.
// Q/K/V layout: [(b*H+h)*N+n][t][d]
__global__ __launch_bounds__(256) void k_qkv(
    const float* __restrict__ query, const float* __restrict__ tepe,
    const float* __restrict__ Wq, const float* __restrict__ Wk, const float* __restrict__ Wv,
    float* __restrict__ Q, float* __restrict__ K, float* __restrict__ V) {
    __shared__ __align__(16) float xs[ROWS_PB][C_];
    int r0 = blockIdx.x * ROWS_PB;
    int tid = threadIdx.x;
    for (int i = tid; i < ROWS_PB * C_; i += 256) {
        int rr = i >> 7, c = i & (C_ - 1);
        int gr = r0 + rr;
        int t = gr % T_;
        int b = gr / (N_ * T_);
        xs[rr][c] = query[gr * C_ + c] + tepe[(b * T_ + t) * C_ + c];
    }
    __syncthreads();
    int c = tid & (C_ - 1);
    int g = tid >> 7;   // 0/1 -> owns rows g*8 .. g*8+7
    float aq[8], ak[8], av[8];
#pragma unroll
    for (int i = 0; i < 8; i++) { aq[i] = 0.f; ak[i] = 0.f; av[i] = 0.f; }
    for (int k = 0; k < C_; k += 4) {
        float wq[4], wk[4], wv[4];
#pragma unroll
        for (int j = 0; j < 4; j++) {
            wq[j] = Wq[(k + j) * C_ + c];
            wk[j] = Wk[(k + j) * C_ + c];
            wv[j] = Wv[(k + j) * C_ + c];
        }
#pragma unroll
        for (int i = 0; i < 8; i++) {
            float4 xv = *(const float4*)&xs[g * 8 + i][k];
            aq[i] += xv.x * wq[0] + xv.y * wq[1] + xv.z * wq[2] + xv.w * wq[3];
            ak[i] += xv.x * wk[0] + xv.y * wk[1] + xv.z * wk[2] + xv.w * wk[3];
            av[i] += xv.x * wv[0] + xv.y * wv[1] + xv.z * wv[2] + xv.w * wv[3];
        }
    }
    int h = c >> 4, d = c & 15;
#pragma unroll
    for (int i = 0; i < 8; i++) {
        int gr = r0 + g * 8 + i;
        int t = gr % T_;
        int n = (gr / T_) % N_;
        int b = gr / (N_ * T_);
        int e = (b * H_ + h) * N_ + n;
        int off = e * (T_ * D_) + t * D_ + d;
        Q[off] = aq[i]; K[off] = ak[i]; V[off] = av[i];
    }
}

// helper: dot of two 16-float LDS rows (16B-aligned)
__device__ inline float dot16(const float* a, const float* b) {
    float4 a0 = *(const float4*)(a), a1 = *(const float4*)(a + 4);
    float4 a2 = *(const float4*)(a + 8), a3 = *(const float4*)(a + 12);
    float4 b0 = *(const float4*)(b), b1 = *(const float4*)(b + 4);
    float4 b2 = *(const float4*)(b + 8), b3 = *(const float4*)(b + 12);
    float s = a0.x * b0.x + a0.y * b0.y + a0.z * b0.z + a0.w * b0.w;
    s += a1.x * b1.x + a1.y * b1.y + a1.z * b1.z + a1.w * b1.w;
    s += a2.x * b2.x + a2.y * b2.y + a2.z * b2.z + a2.w * b2.w;
    s += a3.x * b3.x + a3.y * b3.y + a3.z * b3.z + a3.w * b3.w;
    return s;
}

// ---------------- kernel 2: attention core, one block per (b,h,n)
__global__ __launch_bounds__(128) void k_attn(
    const float* __restrict__ Q, const float* __restrict__ K, const float* __restrict__ V,
    const int* __restrict__ idxs, float* __restrict__ ctx) {
    __shared__ __align__(16) float Qs[T_][D_], Ks[T_][D_], Vs[T_][D_];
    __shared__ float qk[T_][S_ + 1];
    __shared__ float sc[T_][T_ + 1];
    __shared__ float Mv[T_];
    __shared__ int keep[T_];
    __shared__ float meanV[D_];
    __shared__ int sidx[T_ * S_];
    int e = blockIdx.x;
    int tid = threadIdx.x;
    const float* qb = Q + (size_t)e * T_ * D_;
    const float* kb = K + (size_t)e * T_ * D_;
    const float* vb = V + (size_t)e * T_ * D_;
    for (int i = tid; i < T_ * D_; i += 128) {
        ((float*)Qs)[i] = qb[i];
        ((float*)Ks)[i] = kb[i];
        ((float*)Vs)[i] = vb[i];
    }
    for (int i = tid; i < T_ * S_; i += 128) sidx[i] = idxs[i];
    __syncthreads();
    // QK_samp
    for (int i = tid; i < T_ * S_; i += 128) {
        int t = i / S_, s = i - t * S_;
        qk[t][s] = dot16(Qs[t], Ks[sidx[i]]);
    }
    __syncthreads();
    // M[t] = max_s - sum_s/S ; meanV
    if (tid < T_) {
        float mx = -1e30f, sm = 0.f;
        for (int s = 0; s < S_; s++) { float v = qk[tid][s]; mx = fmaxf(mx, v); sm += v; }
        Mv[tid] = mx - sm * (1.0f / S_);
    } else if (tid >= 64 && tid < 64 + D_) {
        int d = tid - 64;
        float s = 0.f;
        for (int t = 0; t < T_; t++) s += Vs[t][d];
        meanV[d] = s * (1.0f / T_);
    }
    __syncthreads();
    // keep mask (top-U as a set, tie-break lower index) + full scores
    if (tid < T_) {
        float mt = Mv[tid];
        int cnt = 0;
        for (int t2 = 0; t2 < T_; t2++) {
            float m2 = Mv[t2];
            cnt += (m2 > mt) || (m2 == mt && t2 < tid);
        }
        keep[tid] = (cnt < U_) ? 1 : 0;
    }
    for (int i = tid; i < T_ * T_; i += 128) {
        int t = i / T_, t2 = i - t * T_;
        sc[t][t2] = 0.25f * dot16(Qs[t], Ks[t2]);   // 1/sqrt(16)
    }
    __syncthreads();
    // softmax per row
    if (tid < T_) {
        float mx = -1e30f;
        for (int t2 = 0; t2 < T_; t2++) mx = fmaxf(mx, sc[tid][t2]);
        float sum = 0.f;
        for (int t2 = 0; t2 < T_; t2++) { float ev = expf(sc[tid][t2] - mx); sc[tid][t2] = ev; sum += ev; }
        float inv = 1.0f / sum;
        for (int t2 = 0; t2 < T_; t2++) sc[tid][t2] *= inv;
    }
    __syncthreads();
    // upd / meanV -> ctx in (B,N,T,C) layout
    int b = e / (H_ * N_);
    int h = (e / N_) % H_;
    int n = e % N_;
    for (int i = tid; i < T_ * D_; i += 128) {
        int t = i >> 4, d = i & 15;
        float o;
        if (keep[t]) {
            float s = 0.f;
            for (int t2 = 0; t2 < T_; t2++) s += sc[t][t2] * Vs[t2][d];
            o = s;
        } else {
            o = meanV[d];
        }
        ctx[((b * N_ + n) * T_ + t) * C_ + h * D_ + d] = o;
    }
}

// ---------------- kernel 3: att_out = ctx@Wo + bo; y = att_out + x; x1 = LN1(y)
__global__ __launch_bounds__(256) void k_out_ln(
    const float* __restrict__ ctx, const float* __restrict__ Wo, const float* __restrict__ bo,
    const float* __restrict__ query, const float* __restrict__ tepe,
    const float* __restrict__ g1, const float* __restrict__ b1,
    float* __restrict__ x1) {
    __shared__ __align__(16) float cs[ROWS_PB][C_];
    __shared__ float yv[ROWS_PB][C_];
    __shared__ float red[ROWS_PB][16];
    __shared__ float mean_[ROWS_PB], rstd_[ROWS_PB];
    int r0 = blockIdx.x * ROWS_PB;
    int tid = threadIdx.x;
    for (int i = tid; i < ROWS_PB * C_; i += 256) {
        int rr = i >> 7, c = i & (C_ - 1);
        cs[rr][c] = ctx[(r0 + rr) * C_ + c];
    }
    __syncthreads();
    int c = tid & (C_ - 1);
    int g = tid >> 7;
    float acc[8];
#pragma unroll
    for (int i = 0; i < 8; i++) acc[i] = 0.f;
    for (int k = 0; k < C_; k += 4) {
        float w[4];
#pragma unroll
        for (int j = 0; j < 4; j++) w[j] = Wo[(k + j) * C_ + c];
#pragma unroll
        for (int i = 0; i < 8; i++) {
            float4 xv = *(const float4*)&cs[g * 8 + i][k];
            acc[i] += xv.x * w[0] + xv.y * w[1] + xv.z * w[2] + xv.w * w[3];
        }
    }
    float boc = bo[c];
#pragma unroll
    for (int i = 0; i < 8; i++) {
        int rr = g * 8 + i;
        int gr = r0 + rr;
        int t = gr % T_;
        int b = gr / (N_ * T_);
        yv[rr][c] = acc[i] + boc + query[gr * C_ + c] + tepe[(b * T_ + t) * C_ + c];
    }
    __syncthreads();
    // LN over C=128 per row
    int r = tid >> 4, s2 = tid & 15;
    float p = 0.f;
    for (int j = 0; j < 8; j++) p += yv[r][s2 + 16 * j];
    red[r][s2] = p;
    __syncthreads();
    if (s2 == 0) {
        float m = 0.f;
        for (int j = 0; j < 16; j++) m += red[r][j];
        mean_[r] = m * (1.0f / C_);
    }
    __syncthreads();
    float mm = mean_[r];
    p = 0.f;
    for (int j = 0; j < 8; j++) { float d = yv[r][s2 + 16 * j] - mm; p += d * d; }
    red[r][s2] = p;
    __syncthreads();
    if (s2 == 0) {
        float v = 0.f;
        for (int j = 0; j < 16; j++) v += red[r][j];
        rstd_[r] = rsqrtf(v * (1.0f / C_) + 1e-5f);
    }
    __syncthreads();
    float gc = g1[c], bc = b1[c];
#pragma unroll
    for (int i = 0; i < 8; i++) {
        int rr = g * 8 + i;
        x1[(r0 + rr) * C_ + c] = (yv[rr][c] - mean_[rr]) * rstd_[rr] * gc + bc;
    }
}

// ---------------- kernel 4: FF (128->512 relu ->128) + residual + LN2 -> out
__global__ __launch_bounds__(256) void k_ff_ln(
    const float* __restrict__ x1, const float* __restrict__ w1, const float* __restrict__ b1f,
    const float* __restrict__ w2, const float* __restrict__ b2f,
    const float* __restrict__ g2, const float* __restrict__ b2ln,
    float* __restrict__ out) {
    __shared__ __align__(16) float xs[ROWS_PB][C_];
    __shared__ __align__(16) float hs[ROWS_PB][FF];
    __shared__ float red[ROWS_PB][16];
    __shared__ float mean_[ROWS_PB], rstd_[ROWS_PB];
    int r0 = blockIdx.x * ROWS_PB;
    int tid = threadIdx.x;
    for (int i = tid; i < ROWS_PB * C_; i += 256) {
        int rr = i >> 7, c = i & (C_ - 1);
        xs[rr][c] = x1[(r0 + rr) * C_ + c];
    }
    __syncthreads();
    // hidden = relu(x1 @ w1 + b1): each thread owns columns tid and tid+256
    for (int jj = 0; jj < 2; jj++) {
        int j = tid + jj * 256;
        float a[ROWS_PB];
#pragma unroll
        for (int r = 0; r < ROWS_PB; r++) a[r] = 0.f;
        for (int k = 0; k < C_; k += 4) {
            float w[4];
#pragma unroll
            for (int q = 0; q < 4; q++) w[q] = w1[(k + q) * FF + j];
#pragma unroll
            for (int r = 0; r < ROWS_PB; r++) {
                float4 xv = *(const float4*)&xs[r][k];
                a[r] += xv.x * w[0] + xv.y * w[1] + xv.z * w[2] + xv.w * w[3];
            }
        }
        float bj = b1f[j];
#pragma unroll
        for (int r = 0; r < ROWS_PB; r++) hs[r][j] = fmaxf(a[r] + bj, 0.f);
    }
    __syncthreads();
    // out = hidden @ w2 + b2 + x1 (residual), then LN2
    int c = tid & (C_ - 1);
    int g = tid >> 7;
    float acc[8];
#pragma unroll
    for (int i = 0; i < 8; i++) acc[i] = 0.f;
    for (int j = 0; j < FF; j += 4) {
        float w[4];
#pragma unroll
        for (int q = 0; q < 4; q++) w[q] = w2[(j + q) * C_ + c];
#pragma unroll
        for (int i = 0; i < 8; i++) {
            float4 hv = *(const float4*)&hs[g * 8 + i][j];
            acc[i] += hv.x * w[0] + hv.y * w[1] + hv.z * w[2] + hv.w * w[3];
        }
    }
    float b2c = b2f[c];
#pragma unroll
    for (int i = 0; i < 8; i++) {
        int rr = g * 8 + i;
        // in-place: each thread overwrites exactly the element it reads
        xs[rr][c] = acc[i] + b2c + xs[rr][c];
    }
    __syncthreads();
    // LN2
    int r = tid >> 4, s2 = tid & 15;
    float p = 0.f;
    for (int j = 0; j < 8; j++) p += xs[r][s2 + 16 * j];
    red[r][s2] = p;
    __syncthreads();
    if (s2 == 0) {
        float m = 0.f;
        for (int j = 0; j < 16; j++) m += red[r][j];
        mean_[r] = m * (1.0f / C_);
    }
    __syncthreads();
    float mm = mean_[r];
    p = 0.f;
    for (int j = 0; j < 8; j++) { float d = xs[r][s2 + 16 * j] - mm; p += d * d; }
    red[r][s2] = p;
    __syncthreads();
    if (s2 == 0) {
        float v = 0.f;
        for (int j = 0; j < 16; j++) v += red[r][j];
        rstd_[r] = rsqrtf(v * (1.0f / C_) + 1e-5f);
    }
    __syncthreads();
    float gc = g2[c], bc = b2ln[c];
#pragma unroll
    for (int i = 0; i < 8; i++) {
        int rr = g * 8 + i;
        out[(r0 + rr) * C_ + c] = (xs[rr][c] - mean_[rr]) * rstd_[rr] * gc + bc;
    }
}

extern "C" void kernel_launch(void* const* d_in, const int* in_sizes, int n_in,
                              void* d_out, int out_size, void* d_ws, size_t ws_size,
                              hipStream_t stream) {
    const float* query = (const float*)d_in[2];
    const int* time_enc = (const int*)d_in[4];
    const int* index_sample = (const int*)d_in[5];
    const float* e_min = (const float*)d_in[6];
    const float* e_hr  = (const float*)d_in[7];
    const float* e_wd  = (const float*)d_in[8];
    const float* e_mo  = (const float*)d_in[9];
    const float* e_yr  = (const float*)d_in[10];
    const float* Wq = (const float*)d_in[11];
    const float* Wk = (const float*)d_in[12];
    const float* Wv = (const float*)d_in[13];
    const float* Wo = (const float*)d_in[14];
    const float* bo = (const float*)d_in[15];
    const float* ffw1 = (const float*)d_in[16];
    const float* ffb1 = (const float*)d_in[17];
    const float* ffw2 = (const float*)d_in[18];
    const float* ffb2 = (const float*)d_in[19];
    const float* ln1g = (const float*)d_in[20];
    const float* ln1b = (const float*)d_in[21];
    const float* ln2g = (const float*)d_in[22];
    const float* ln2b = (const float*)d_in[23];

    float* ws = (float*)d_ws;
    float* tepe = ws;                 // 49152
    float* Qb = ws + TEPE_N;          // NX
    float* Kb = Qb + NX;              // NX
    float* Vb = Kb + NX;              // NX
    float* ctxb = Vb + NX;            // NX
    float* x1 = Qb;                   // reuse Q after attention

    k_tepe<<<dim3((TEPE_N + 255) / 256), dim3(256), 0, stream>>>(
        time_enc, e_min, e_hr, e_wd, e_mo, e_yr, tepe);
    k_qkv<<<dim3(NBLK_ROWS), dim3(256), 0, stream>>>(
        query, tepe, Wq, Wk, Wv, Qb, Kb, Vb);
    k_attn<<<dim3(B_ * H_ * N_), dim3(128), 0, stream>>>(
        Qb, Kb, Vb, index_sample, ctxb);
    k_out_ln<<<dim3(NBLK_ROWS), dim3(256), 0, stream>>>(
        ctxb, Wo, bo, query, tepe, ln1g, ln1b, x1);
    k_ff_ln<<<dim3(NBLK_ROWS), dim3(256), 0, stream>>>(
        x1, ffw1, ffb1, ffw2, ffb2, ln2g, ln2b, (float*)d_out);
}

// Round 2
// 752.893 us; speedup vs baseline: 1.5698x; 1.5698x over previous
//
#include <hip/hip_runtime.h>
#include <hip/hip_bf16.h>
#include <cmath>

namespace {
constexpr int B_ = 16, N_ = 307, T_ = 24, C_ = 128, H_ = 8, D_ = 16, S_ = 20, U_ = 20;
constexpr int NROW = B_ * N_ * T_;          // 117888
constexpr int NX = NROW * C_;               // 15089664
constexpr int TEPE_N = B_ * T_ * C_;        // 49152
constexpr int ROWS_PB = 16;                 // rows per block for row-tiled kernels
constexpr int NBLK_ROWS = NROW / ROWS_PB;   // 7368
constexpr int FF = 4 * C_;                  // 512
constexpr int BM = 32;                      // rows per FF-MFMA block
constexpr int NBLK_FF = NROW / BM;          // 3684
}

typedef __attribute__((ext_vector_type(8))) short short8;
typedef __attribute__((ext_vector_type(4))) short short4_;
typedef __attribute__((ext_vector_type(4))) float f32x4;

__device__ inline short f2bf(float v) {
    union { float f; unsigned u; } a; a.f = v;
    unsigned r = a.u + 0x7fff + ((a.u >> 16) & 1);   // round-to-nearest-even
    return (short)(r >> 16);
}

// ---------------- kernel 0: tepe[b,t,c] = pos_emb(t,c) + sum of 5 embedding lookups
__global__ void k_tepe(const int* __restrict__ te,
                       const float* __restrict__ e_min, const float* __restrict__ e_hr,
                       const float* __restrict__ e_wd, const float* __restrict__ e_mo,
                       const float* __restrict__ e_yr, float* __restrict__ tepe) {
    int i = blockIdx.x * blockDim.x + threadIdx.x;
    if (i >= TEPE_N) return;
    int c = i & (C_ - 1);
    int bt = i >> 7;              // b*T + t
    int t = bt % T_;
    const int* enc = te + bt * 5;
    float v = e_min[enc[0] * C_ + c] + e_hr[enc[1] * C_ + c] + e_wd[enc[2] * C_ + c]
            + e_mo[enc[3] * C_ + c] + e_yr[enc[4] * C_ + c];
    float ang = (float)t * expf(-(float)(c & ~1) * (9.210340371976184f / 128.0f));
    v += (c & 1) ? cosf(ang) : sinf(ang);
    tepe[i] = v;
}

// ---------------- kernel 1: QKV projection. x recomputed on the fly.
// Q/K/V layout: [(b*H+h)*N+n][t][d]
__global__ __launch_bounds__(256) void k_qkv(
    const float* __restrict__ query, const float* __restrict__ tepe,
    const float* __restrict__ Wq, const float* __restrict__ Wk, const float* __restrict__ Wv,
    float* __restrict__ Q, float* __restrict__ K, float* __restrict__ V) {
    __shared__ __align__(16) float xs[ROWS_PB][C_];
    int r0 = blockIdx.x * ROWS_PB;
    int tid = threadIdx.x;
    for (int i = tid; i < ROWS_PB * C_; i += 256) {
        int rr = i >> 7, c = i & (C_ - 1);
        int gr = r0 + rr;
        int t = gr % T_;
        int b = gr / (N_ * T_);
        xs[rr][c] = query[gr * C_ + c] + tepe[(b * T_ + t) * C_ + c];
    }
    __syncthreads();
    int c = tid & (C_ - 1);
    int g = tid >> 7;   // 0/1 -> owns rows g*8 .. g*8+7
    float aq[8], ak[8], av[8];
#pragma unroll
    for (int i = 0; i < 8; i++) { aq[i] = 0.f; ak[i] = 0.f; av[i] = 0.f; }
    for (int k = 0; k < C_; k += 4) {
        float wq[4], wk[4], wv[4];
#pragma unroll
        for (int j = 0; j < 4; j++) {
            wq[j] = Wq[(k + j) * C_ + c];
            wk[j] = Wk[(k + j) * C_ + c];
            wv[j] = Wv[(k + j) * C_ + c];
        }
#pragma unroll
        for (int i = 0; i < 8; i++) {
            float4 xv = *(const float4*)&xs[g * 8 + i][k];
            aq[i] += xv.x * wq[0] + xv.y * wq[1] + xv.z * wq[2] + xv.w * wq[3];
            ak[i] += xv.x * wk[0] + xv.y * wk[1] + xv.z * wk[2] + xv.w * wk[3];
            av[i] += xv.x * wv[0] + xv.y * wv[1] + xv.z * wv[2] + xv.w * wv[3];
        }
    }
    int h = c >> 4, d = c & 15;
#pragma unroll
    for (int i = 0; i < 8; i++) {
        int gr = r0 + g * 8 + i;
        int t = gr % T_;
        int n = (gr / T_) % N_;
        int b = gr / (N_ * T_);
        int e = (b * H_ + h) * N_ + n;
        int off = e * (T_ * D_) + t * D_ + d;
        Q[off] = aq[i]; K[off] = ak[i]; V[off] = av[i];
    }
}

// helper: dot of two 16-float LDS rows (16B-aligned)
__device__ inline float dot16(const float* a, const float* b) {
    float4 a0 = *(const float4*)(a), a1 = *(const float4*)(a + 4);
    float4 a2 = *(const float4*)(a + 8), a3 = *(const float4*)(a + 12);
    float4 b0 = *(const float4*)(b), b1 = *(const float4*)(b + 4);
    float4 b2 = *(const float4*)(b + 8), b3 = *(const float4*)(b + 12);
    float s = a0.x * b0.x + a0.y * b0.y + a0.z * b0.z + a0.w * b0.w;
    s += a1.x * b1.x + a1.y * b1.y + a1.z * b1.z + a1.w * b1.w;
    s += a2.x * b2.x + a2.y * b2.y + a2.z * b2.z + a2.w * b2.w;
    s += a3.x * b3.x + a3.y * b3.y + a3.z * b3.z + a3.w * b3.w;
    return s;
}

// ---------------- kernel 2: attention core, one block per (b,h,n)
__global__ __launch_bounds__(128) void k_attn(
    const float* __restrict__ Q, const float* __restrict__ K, const float* __restrict__ V,
    const int* __restrict__ idxs, float* __restrict__ ctx) {
    __shared__ __align__(16) float Qs[T_][D_], Ks[T_][D_], Vs[T_][D_];
    __shared__ float qk[T_][S_ + 1];
    __shared__ float sc[T_][T_ + 1];
    __shared__ float Mv[T_];
    __shared__ int keep[T_];
    __shared__ float meanV[D_];
    __shared__ int sidx[T_ * S_];
    int e = blockIdx.x;
    int tid = threadIdx.x;
    const float* qb = Q + (size_t)e * T_ * D_;
    const float* kb = K + (size_t)e * T_ * D_;
    const float* vb = V + (size_t)e * T_ * D_;
    for (int i = tid; i < T_ * D_; i += 128) {
        ((float*)Qs)[i] = qb[i];
        ((float*)Ks)[i] = kb[i];
        ((float*)Vs)[i] = vb[i];
    }
    for (int i = tid; i < T_ * S_; i += 128) sidx[i] = idxs[i];
    __syncthreads();
    // QK_samp
    for (int i = tid; i < T_ * S_; i += 128) {
        int t = i / S_, s = i - t * S_;
        qk[t][s] = dot16(Qs[t], Ks[sidx[i]]);
    }
    __syncthreads();
    // M[t] = max_s - sum_s/S ; meanV
    if (tid < T_) {
        float mx = -1e30f, sm = 0.f;
        for (int s = 0; s < S_; s++) { float v = qk[tid][s]; mx = fmaxf(mx, v); sm += v; }
        Mv[tid] = mx - sm * (1.0f / S_);
    } else if (tid >= 64 && tid < 64 + D_) {
        int d = tid - 64;
        float s = 0.f;
        for (int t = 0; t < T_; t++) s += Vs[t][d];
        meanV[d] = s * (1.0f / T_);
    }
    __syncthreads();
    // keep mask (top-U as a set, tie-break lower index) + full scores
    if (tid < T_) {
        float mt = Mv[tid];
        int cnt = 0;
        for (int t2 = 0; t2 < T_; t2++) {
            float m2 = Mv[t2];
            cnt += (m2 > mt) || (m2 == mt && t2 < tid);
        }
        keep[tid] = (cnt < U_) ? 1 : 0;
    }
    for (int i = tid; i < T_ * T_; i += 128) {
        int t = i / T_, t2 = i - t * T_;
        sc[t][t2] = 0.25f * dot16(Qs[t], Ks[t2]);   // 1/sqrt(16)
    }
    __syncthreads();
    // softmax per row
    if (tid < T_) {
        float mx = -1e30f;
        for (int t2 = 0; t2 < T_; t2++) mx = fmaxf(mx, sc[tid][t2]);
        float sum = 0.f;
        for (int t2 = 0; t2 < T_; t2++) { float ev = expf(sc[tid][t2] - mx); sc[tid][t2] = ev; sum += ev; }
        float inv = 1.0f / sum;
        for (int t2 = 0; t2 < T_; t2++) sc[tid][t2] *= inv;
    }
    __syncthreads();
    // upd / meanV -> ctx in (B,N,T,C) layout
    int b = e / (H_ * N_);
    int h = (e / N_) % H_;
    int n = e % N_;
    for (int i = tid; i < T_ * D_; i += 128) {
        int t = i >> 4, d = i & 15;
        float o;
        if (keep[t]) {
            float s = 0.f;
            for (int t2 = 0; t2 < T_; t2++) s += sc[t][t2] * Vs[t2][d];
            o = s;
        } else {
            o = meanV[d];
        }
        ctx[((b * N_ + n) * T_ + t) * C_ + h * D_ + d] = o;
    }
}

// ---------------- kernel 3: att_out = ctx@Wo + bo; y = att_out + x; x1 = LN1(y)
__global__ __launch_bounds__(256) void k_out_ln(
    const float* __restrict__ ctx, const float* __restrict__ Wo, const float* __restrict__ bo,
    const float* __restrict__ query, const float* __restrict__ tepe,
    const float* __restrict__ g1, const float* __restrict__ b1,
    float* __restrict__ x1) {
    __shared__ __align__(16) float cs[ROWS_PB][C_];
    __shared__ float yv[ROWS_PB][C_];
    __shared__ float red[ROWS_PB][16];
    __shared__ float mean_[ROWS_PB], rstd_[ROWS_PB];
    int r0 = blockIdx.x * ROWS_PB;
    int tid = threadIdx.x;
    for (int i = tid; i < ROWS_PB * C_; i += 256) {
        int rr = i >> 7, c = i & (C_ - 1);
        cs[rr][c] = ctx[(r0 + rr) * C_ + c];
    }
    __syncthreads();
    int c = tid & (C_ - 1);
    int g = tid >> 7;
    float acc[8];
#pragma unroll
    for (int i = 0; i < 8; i++) acc[i] = 0.f;
    for (int k = 0; k < C_; k += 4) {
        float w[4];
#pragma unroll
        for (int j = 0; j < 4; j++) w[j] = Wo[(k + j) * C_ + c];
#pragma unroll
        for (int i = 0; i < 8; i++) {
            float4 xv = *(const float4*)&cs[g * 8 + i][k];
            acc[i] += xv.x * w[0] + xv.y * w[1] + xv.z * w[2] + xv.w * w[3];
        }
    }
    float boc = bo[c];
#pragma unroll
    for (int i = 0; i < 8; i++) {
        int rr = g * 8 + i;
        int gr = r0 + rr;
        int t = gr % T_;
        int b = gr / (N_ * T_);
        yv[rr][c] = acc[i] + boc + query[gr * C_ + c] + tepe[(b * T_ + t) * C_ + c];
    }
    __syncthreads();
    // LN over C=128 per row
    int r = tid >> 4, s2 = tid & 15;
    float p = 0.f;
    for (int j = 0; j < 8; j++) p += yv[r][s2 + 16 * j];
    red[r][s2] = p;
    __syncthreads();
    if (s2 == 0) {
        float m = 0.f;
        for (int j = 0; j < 16; j++) m += red[r][j];
        mean_[r] = m * (1.0f / C_);
    }
    __syncthreads();
    float mm = mean_[r];
    p = 0.f;
    for (int j = 0; j < 8; j++) { float d = yv[r][s2 + 16 * j] - mm; p += d * d; }
    red[r][s2] = p;
    __syncthreads();
    if (s2 == 0) {
        float v = 0.f;
        for (int j = 0; j < 16; j++) v += red[r][j];
        rstd_[r] = rsqrtf(v * (1.0f / C_) + 1e-5f);
    }
    __syncthreads();
    float gc = g1[c], bc = b1[c];
#pragma unroll
    for (int i = 0; i < 8; i++) {
        int rr = g * 8 + i;
        x1[(r0 + rr) * C_ + c] = (yv[rr][c] - mean_[rr]) * rstd_[rr] * gc + bc;
    }
}

// ---------------- kernel 4a: convert FF weights to bf16, transposed
// w1t[j][k] = bf16(w1[k][j])  (512x128);  w2t[c][j] = bf16(w2[j][c])  (128x512)
__global__ void k_wcvt(const float* __restrict__ w1, const float* __restrict__ w2,
                       short* __restrict__ w1t, short* __restrict__ w2t) {
    int i = blockIdx.x * 256 + threadIdx.x;
    if (i < C_ * FF) {
        int j = i >> 7, k = i & (C_ - 1);
        w1t[i] = f2bf(w1[k * FF + j]);
    } else {
        int i2 = i - C_ * FF;
        int c = i2 >> 9, j = i2 & (FF - 1);
        w2t[i2] = f2bf(w2[j * C_ + c]);
    }
}

// ---------------- kernel 4: FF via bf16 MFMA + residual + LN2 -> out
// GEMM1 computes hiddenT tiles:  D[j][r] = sum_k w1t[j][k] * x[r][k]
//   -> lane holds 4 consecutive j at fixed r -> one ds_write_b64 into row-major hbf[r][j]
// GEMM2 computes outT tiles:     D[c][r] = sum_j w2t[c][j] * hidden[r][j]
//   -> lane holds 4 consecutive c at fixed r -> float4 residual+store into xf[r][c]
__global__ __launch_bounds__(256) void k_ff_mfma(
    const float* __restrict__ x1, const short* __restrict__ w1t, const float* __restrict__ b1f,
    const short* __restrict__ w2t, const float* __restrict__ b2f,
    const float* __restrict__ g2, const float* __restrict__ b2ln,
    float* __restrict__ out) {
    __shared__ __align__(16) short xbf[BM * C_];     // bf16 x, swizzled
    __shared__ __align__(16) float xf[BM][132];      // f32 x (residual), later y
    __shared__ __align__(16) short hbf[BM * FF];     // bf16 hidden, swizzled
    int tid = threadIdx.x;
    int r0 = blockIdx.x * BM;
    // ---- load x tile
    {
        int row = tid >> 3;                 // 0..31
        int cb = (tid & 7) * 16;
        const float* src = x1 + (size_t)(r0 + row) * C_ + cb;
#pragma unroll
        for (int i = 0; i < 4; i++) {
            float4 v = *(const float4*)(src + 4 * i);
            *(float4*)&xf[row][cb + 4 * i] = v;
            int idx = (row * C_ + cb + 4 * i) ^ ((row & 7) << 3);
            short4_ sv;
            sv.x = f2bf(v.x); sv.y = f2bf(v.y); sv.z = f2bf(v.z); sv.w = f2bf(v.w);
            *(short4_*)&xbf[idx] = sv;
        }
    }
    __syncthreads();
    int w = tid >> 6, l = tid & 63;
    int lr = l & 15, lk = l >> 4;           // lk in 0..3
    int rt = w & 1;
    int rrow = rt * 16 + lr;                // this wave's row (as MFMA N-dim lane)
    // ---- GEMM1: hidden
    {
        short8 bx[4];
#pragma unroll
        for (int ks = 0; ks < 4; ks++) {
            int k0 = ks * 32 + lk * 8;
            bx[ks] = *(const short8*)&xbf[(rrow * C_ + k0) ^ ((rrow & 7) << 3)];
        }
        int j0base = (w >> 1) * 256;
#pragma unroll 2
        for (int jt = 0; jt < 16; jt++) {
            const short* ap = w1t + (size_t)(j0base + jt * 16 + lr) * C_;
            f32x4 acc = {0.f, 0.f, 0.f, 0.f};
#pragma unroll
            for (int ks = 0; ks < 4; ks++) {
                short8 af = *(const short8*)(ap + ks * 32 + lk * 8);
                acc = __builtin_amdgcn_mfma_f32_16x16x32_bf16(af, bx[ks], acc, 0, 0, 0);
            }
            int j0 = j0base + jt * 16 + lk * 4;     // 4 consecutive hidden cols
            float4 bias = *(const float4*)(b1f + j0);
            short4_ hv;
            hv.x = f2bf(fmaxf(acc.x + bias.x, 0.f));
            hv.y = f2bf(fmaxf(acc.y + bias.y, 0.f));
            hv.z = f2bf(fmaxf(acc.z + bias.z, 0.f));
            hv.w = f2bf(fmaxf(acc.w + bias.w, 0.f));
            *(short4_*)&hbf[(rrow * FF + j0) ^ ((rrow & 7) << 3)] = hv;
        }
    }
    __syncthreads();
    // ---- GEMM2: out = hidden @ w2 (+bias +residual)
    {
        short8 bh[16];
#pragma unroll
        for (int ks = 0; ks < 16; ks++) {
            int k0 = ks * 32 + lk * 8;
            bh[ks] = *(const short8*)&hbf[(rrow * FF + k0) ^ ((rrow & 7) << 3)];
        }
        int c0base = (w >> 1) * 64;
#pragma unroll
        for (int ct = 0; ct < 4; ct++) {
            const short* ap = w2t + (size_t)(c0base + ct * 16 + lr) * FF;
            f32x4 acc = {0.f, 0.f, 0.f, 0.f};
#pragma unroll
            for (int ks = 0; ks < 16; ks++) {
                short8 af = *(const short8*)(ap + ks * 32 + lk * 8);
                acc = __builtin_amdgcn_mfma_f32_16x16x32_bf16(af, bh[ks], acc, 0, 0, 0);
            }
            int cc = c0base + ct * 16 + lk * 4;     // 4 consecutive out cols
            float4 bias = *(const float4*)(b2f + cc);
            float4 res = *(const float4*)&xf[rrow][cc];
            float4 o;
            o.x = acc.x + bias.x + res.x;
            o.y = acc.y + bias.y + res.y;
            o.z = acc.z + bias.z + res.z;
            o.w = acc.w + bias.w + res.w;
            *(float4*)&xf[rrow][cc] = o;
        }
    }
    __syncthreads();
    // ---- LN2 + store
    {
        int r = tid >> 3;
        int q = tid & 7;
        int cb = q * 16;
        float vals[16];
        float s = 0.f;
#pragma unroll
        for (int i = 0; i < 16; i++) { vals[i] = xf[r][cb + i]; s += vals[i]; }
        s += __shfl_xor(s, 1, 8);
        s += __shfl_xor(s, 2, 8);
        s += __shfl_xor(s, 4, 8);
        float mean = s * (1.f / C_);
        float vv = 0.f;
#pragma unroll
        for (int i = 0; i < 16; i++) { float d = vals[i] - mean; vv += d * d; }
        vv += __shfl_xor(vv, 1, 8);
        vv += __shfl_xor(vv, 2, 8);
        vv += __shfl_xor(vv, 4, 8);
        float rstd = rsqrtf(vv * (1.f / C_) + 1e-5f);
        float* op = out + (size_t)(r0 + r) * C_ + cb;
#pragma unroll
        for (int i4 = 0; i4 < 4; i4++) {
            float4 gv = *(const float4*)(g2 + cb + 4 * i4);
            float4 bv = *(const float4*)(b2ln + cb + 4 * i4);
            float4 ov;
            ov.x = (vals[4 * i4 + 0] - mean) * rstd * gv.x + bv.x;
            ov.y = (vals[4 * i4 + 1] - mean) * rstd * gv.y + bv.y;
            ov.z = (vals[4 * i4 + 2] - mean) * rstd * gv.z + bv.z;
            ov.w = (vals[4 * i4 + 3] - mean) * rstd * gv.w + bv.w;
            *(float4*)(op + 4 * i4) = ov;
        }
    }
}

extern "C" void kernel_launch(void* const* d_in, const int* in_sizes, int n_in,
                              void* d_out, int out_size, void* d_ws, size_t ws_size,
                              hipStream_t stream) {
    const float* query = (const float*)d_in[2];
    const int* time_enc = (const int*)d_in[4];
    const int* index_sample = (const int*)d_in[5];
    const float* e_min = (const float*)d_in[6];
    const float* e_hr  = (const float*)d_in[7];
    const float* e_wd  = (const float*)d_in[8];
    const float* e_mo  = (const float*)d_in[9];
    const float* e_yr  = (const float*)d_in[10];
    const float* Wq = (const float*)d_in[11];
    const float* Wk = (const float*)d_in[12];
    const float* Wv = (const float*)d_in[13];
    const float* Wo = (const float*)d_in[14];
    const float* bo = (const float*)d_in[15];
    const float* ffw1 = (const float*)d_in[16];
    const float* ffb1 = (const float*)d_in[17];
    const float* ffw2 = (const float*)d_in[18];
    const float* ffb2 = (const float*)d_in[19];
    const float* ln1g = (const float*)d_in[20];
    const float* ln1b = (const float*)d_in[21];
    const float* ln2g = (const float*)d_in[22];
    const float* ln2b = (const float*)d_in[23];

    float* ws = (float*)d_ws;
    float* tepe = ws;                 // 49152
    float* Qb = ws + TEPE_N;          // NX
    float* Kb = Qb + NX;              // NX
    float* Vb = Kb + NX;              // NX
    float* ctxb = Vb + NX;            // NX
    float* x1 = Qb;                   // reuse Q after attention

    k_tepe<<<dim3((TEPE_N + 255) / 256), dim3(256), 0, stream>>>(
        time_enc, e_min, e_hr, e_wd, e_mo, e_yr, tepe);
    k_qkv<<<dim3(NBLK_ROWS), dim3(256), 0, stream>>>(
        query, tepe, Wq, Wk, Wv, Qb, Kb, Vb);
    k_attn<<<dim3(B_ * H_ * N_), dim3(128), 0, stream>>>(
        Qb, Kb, Vb, index_sample, ctxb);
    k_out_ln<<<dim3(NBLK_ROWS), dim3(256), 0, stream>>>(
        ctxb, Wo, bo, query, tepe, ln1g, ln1b, x1);
    // ctx is dead now: reuse its space for bf16 transposed FF weights
    short* w1t = (short*)ctxb;
    short* w2t = w1t + C_ * FF;
    k_wcvt<<<dim3(512), dim3(256), 0, stream>>>(ffw1, ffw2, w1t, w2t);
    k_ff_mfma<<<dim3(NBLK_FF), dim3(256), 0, stream>>>(
        x1, w1t, ffb1, w2t, ffb2, ln2g, ln2b, (float*)d_out);
}

// Round 3
// 583.200 us; speedup vs baseline: 2.0266x; 1.2910x over previous
//
#include <hip/hip_runtime.h>
#include <hip/hip_bf16.h>
#include <cmath>

namespace {
constexpr int B_ = 16, N_ = 307, T_ = 24, C_ = 128, H_ = 8, D_ = 16, S_ = 20, U_ = 20;
constexpr int NROW = B_ * N_ * T_;          // 117888
constexpr int NX = NROW * C_;               // 15089664
constexpr int TEPE_N = B_ * T_ * C_;        // 49152
constexpr int FF = 4 * C_;                  // 512
constexpr int BM = 32;                      // rows per MFMA block
constexpr int NBLK_MM = NROW / BM;          // 3684
}

typedef __attribute__((ext_vector_type(8))) short short8;
typedef __attribute__((ext_vector_type(4))) short short4_;
typedef __attribute__((ext_vector_type(4))) float f32x4;

__device__ inline short f2bf(float v) {
    union { float f; unsigned u; } a; a.f = v;
    unsigned r = a.u + 0x7fff + ((a.u >> 16) & 1);   // round-to-nearest-even
    return (short)(r >> 16);
}

// ---------------- kernel 0: tepe[b,t,c] = pos_emb(t,c) + sum of 5 embedding lookups
__global__ void k_tepe(const int* __restrict__ te,
                       const float* __restrict__ e_min, const float* __restrict__ e_hr,
                       const float* __restrict__ e_wd, const float* __restrict__ e_mo,
                       const float* __restrict__ e_yr, float* __restrict__ tepe) {
    int i = blockIdx.x * blockDim.x + threadIdx.x;
    if (i >= TEPE_N) return;
    int c = i & (C_ - 1);
    int bt = i >> 7;              // b*T + t
    int t = bt % T_;
    const int* enc = te + bt * 5;
    float v = e_min[enc[0] * C_ + c] + e_hr[enc[1] * C_ + c] + e_wd[enc[2] * C_ + c]
            + e_mo[enc[3] * C_ + c] + e_yr[enc[4] * C_ + c];
    float ang = (float)t * expf(-(float)(c & ~1) * (9.210340371976184f / 128.0f));
    v += (c & 1) ? cosf(ang) : sinf(ang);
    tepe[i] = v;
}

// ---------------- kernel 0b: xbf = bf16(query + tepe), one float4 per thread
__global__ void k_xprep(const float* __restrict__ query, const float* __restrict__ tepe,
                        short* __restrict__ xbf) {
    int i = blockIdx.x * 256 + threadIdx.x;     // i indexes float4s; NX/4 total
    int c4 = i & 31;
    int gr = i >> 5;
    int t = gr % T_;
    int b = gr / (N_ * T_);
    float4 q = *(const float4*)(query + 4 * (size_t)i);
    float4 p = *(const float4*)(tepe + (size_t)(b * T_ + t) * C_ + c4 * 4);
    short4_ s;
    s.x = f2bf(q.x + p.x); s.y = f2bf(q.y + p.y);
    s.z = f2bf(q.z + p.z); s.w = f2bf(q.w + p.w);
    *(short4_*)&xbf[4 * (size_t)i] = s;
}

// ---------------- weight converts
// wqkvT[c_all][k] = bf16(W{m}[k][c]), c_all in [0,384), m=c_all>>7, c=c_all&127
__global__ void k_wcvt_qkv(const float* __restrict__ Wq, const float* __restrict__ Wk,
                           const float* __restrict__ Wv, short* __restrict__ wqkvT) {
    int i = blockIdx.x * 256 + threadIdx.x;     // 49152
    int c_all = i >> 7, k = i & (C_ - 1);
    int m = c_all >> 7, c = c_all & (C_ - 1);
    const float* W = (m == 0) ? Wq : (m == 1) ? Wk : Wv;
    wqkvT[i] = f2bf(W[k * C_ + c]);
}

// w1t[j][k]=bf16(w1[k][j]) (512x128); w2t[c][j]=bf16(w2[j][c]) (128x512); woT[c][k]=bf16(Wo[k][c])
__global__ void k_wcvt2(const float* __restrict__ w1, const float* __restrict__ w2,
                        const float* __restrict__ Wo,
                        short* __restrict__ w1t, short* __restrict__ w2t,
                        short* __restrict__ woT) {
    int i = blockIdx.x * 256 + threadIdx.x;     // 147456
    if (i < C_ * FF) {
        int j = i >> 7, k = i & (C_ - 1);
        w1t[i] = f2bf(w1[k * FF + j]);
    } else if (i < 2 * C_ * FF) {
        int i2 = i - C_ * FF;
        int c = i2 >> 9, j = i2 & (FF - 1);
        w2t[i2] = f2bf(w2[j * C_ + c]);
    } else {
        int i3 = i - 2 * C_ * FF;
        int c = i3 >> 7, k = i3 & (C_ - 1);
        woT[i3] = f2bf(Wo[k * C_ + c]);
    }
}

// ---------------- kernel 1: QKV projection via MFMA
// D[c_all][r] = sum_k wqkvT[c_all][k] * x[r][k]; lane holds 4 consecutive c_all at fixed row
__global__ __launch_bounds__(256) void k_qkv_mfma(
    const short* __restrict__ xbf, const short* __restrict__ wqkvT,
    float* __restrict__ Q, float* __restrict__ K, float* __restrict__ V) {
    __shared__ __align__(16) short xs[BM * C_];
    int tid = threadIdx.x;
    int r0 = blockIdx.x * BM;
    {
        int row = tid >> 3;                 // 0..31
        int cb = (tid & 7) * 16;
        const short* src = xbf + (size_t)(r0 + row) * C_ + cb;
        short8 v0 = *(const short8*)(src);
        short8 v1 = *(const short8*)(src + 8);
        *(short8*)&xs[(row * C_ + cb) ^ ((row & 7) << 3)] = v0;
        *(short8*)&xs[(row * C_ + cb + 8) ^ ((row & 7) << 3)] = v1;
    }
    __syncthreads();
    int w = tid >> 6, l = tid & 63;
    int lr = l & 15, lk = l >> 4;
    int rt = w & 1;
    int rrow = rt * 16 + lr;
    short8 bx[4];
#pragma unroll
    for (int ks = 0; ks < 4; ks++)
        bx[ks] = *(const short8*)&xs[(rrow * C_ + ks * 32 + lk * 8) ^ ((rrow & 7) << 3)];
    int gr = r0 + rrow;
    int t = gr % T_;
    int n = (gr / T_) % N_;
    int b = gr / (N_ * T_);
    size_t base = ((size_t)b * H_ * N_ + n) * (T_ * D_) + t * D_;
    int cg = w >> 1;
#pragma unroll
    for (int jt = 0; jt < 12; jt++) {
        int c_all0 = (cg * 12 + jt) * 16;       // tile base col in [0,384)
        const short* ap = wqkvT + (size_t)(c_all0 + lr) * C_;
        f32x4 acc = {0.f, 0.f, 0.f, 0.f};
#pragma unroll
        for (int ks = 0; ks < 4; ks++) {
            short8 af = *(const short8*)(ap + ks * 32 + lk * 8);
            acc = __builtin_amdgcn_mfma_f32_16x16x32_bf16(af, bx[ks], acc, 0, 0, 0);
        }
        int c0 = c_all0 + lk * 4;
        int m = c0 >> 7;
        int c = c0 & (C_ - 1);
        int h = c >> 4, d = c & 15;
        float* dst = (m == 0) ? Q : (m == 1) ? K : V;
        *(float4*)&dst[base + (size_t)h * (N_ * T_ * D_) + d] = *(float4*)&acc;
    }
}

// helper: dot of two 16-float LDS rows (16B-aligned)
__device__ inline float dot16(const float* a, const float* b) {
    float4 a0 = *(const float4*)(a), a1 = *(const float4*)(a + 4);
    float4 a2 = *(const float4*)(a + 8), a3 = *(const float4*)(a + 12);
    float4 b0 = *(const float4*)(b), b1 = *(const float4*)(b + 4);
    float4 b2 = *(const float4*)(b + 8), b3 = *(const float4*)(b + 12);
    float s = a0.x * b0.x + a0.y * b0.y + a0.z * b0.z + a0.w * b0.w;
    s += a1.x * b1.x + a1.y * b1.y + a1.z * b1.z + a1.w * b1.w;
    s += a2.x * b2.x + a2.y * b2.y + a2.z * b2.z + a2.w * b2.w;
    s += a3.x * b3.x + a3.y * b3.y + a3.z * b3.z + a3.w * b3.w;
    return s;
}

// ---------------- kernel 2: attention core, one block per (b,h,n)
__global__ __launch_bounds__(128) void k_attn(
    const float* __restrict__ Q, const float* __restrict__ K, const float* __restrict__ V,
    const int* __restrict__ idxs, float* __restrict__ ctx) {
    __shared__ __align__(16) float Qs[T_][D_], Ks[T_][D_], Vs[T_][D_];
    __shared__ float qk[T_][S_ + 1];
    __shared__ float sc[T_][T_ + 1];
    __shared__ float Mv[T_];
    __shared__ int keep[T_];
    __shared__ float meanV[D_];
    __shared__ int sidx[T_ * S_];
    int e = blockIdx.x;
    int tid = threadIdx.x;
    const float* qb = Q + (size_t)e * T_ * D_;
    const float* kb = K + (size_t)e * T_ * D_;
    const float* vb = V + (size_t)e * T_ * D_;
    for (int i = tid; i < T_ * D_; i += 128) {
        ((float*)Qs)[i] = qb[i];
        ((float*)Ks)[i] = kb[i];
        ((float*)Vs)[i] = vb[i];
    }
    for (int i = tid; i < T_ * S_; i += 128) sidx[i] = idxs[i];
    __syncthreads();
    for (int i = tid; i < T_ * S_; i += 128) {
        int t = i / S_, s = i - t * S_;
        qk[t][s] = dot16(Qs[t], Ks[sidx[i]]);
    }
    __syncthreads();
    if (tid < T_) {
        float mx = -1e30f, sm = 0.f;
        for (int s = 0; s < S_; s++) { float v = qk[tid][s]; mx = fmaxf(mx, v); sm += v; }
        Mv[tid] = mx - sm * (1.0f / S_);
    } else if (tid >= 64 && tid < 64 + D_) {
        int d = tid - 64;
        float s = 0.f;
        for (int t = 0; t < T_; t++) s += Vs[t][d];
        meanV[d] = s * (1.0f / T_);
    }
    __syncthreads();
    if (tid < T_) {
        float mt = Mv[tid];
        int cnt = 0;
        for (int t2 = 0; t2 < T_; t2++) {
            float m2 = Mv[t2];
            cnt += (m2 > mt) || (m2 == mt && t2 < tid);
        }
        keep[tid] = (cnt < U_) ? 1 : 0;
    }
    for (int i = tid; i < T_ * T_; i += 128) {
        int t = i / T_, t2 = i - t * T_;
        sc[t][t2] = 0.25f * dot16(Qs[t], Ks[t2]);   // 1/sqrt(16)
    }
    __syncthreads();
    if (tid < T_) {
        float mx = -1e30f;
        for (int t2 = 0; t2 < T_; t2++) mx = fmaxf(mx, sc[tid][t2]);
        float sum = 0.f;
        for (int t2 = 0; t2 < T_; t2++) { float ev = expf(sc[tid][t2] - mx); sc[tid][t2] = ev; sum += ev; }
        float inv = 1.0f / sum;
        for (int t2 = 0; t2 < T_; t2++) sc[tid][t2] *= inv;
    }
    __syncthreads();
    int b = e / (H_ * N_);
    int h = (e / N_) % H_;
    int n = e % N_;
    for (int i = tid; i < T_ * D_; i += 128) {
        int t = i >> 4, d = i & 15;
        float o;
        if (keep[t]) {
            float s = 0.f;
            for (int t2 = 0; t2 < T_; t2++) s += sc[t][t2] * Vs[t2][d];
            o = s;
        } else {
            o = meanV[d];
        }
        ctx[((b * N_ + n) * T_ + t) * C_ + h * D_ + d] = o;
    }
}

// ---------------- kernel 3: att_out = ctx@Wo + bo (MFMA); y = att_out + x; x1 = LN1(y)
__global__ __launch_bounds__(256) void k_out_ln_mfma(
    const float* __restrict__ ctx, const short* __restrict__ woT, const float* __restrict__ bo,
    const float* __restrict__ query, const float* __restrict__ tepe,
    const float* __restrict__ g1, const float* __restrict__ b1,
    float* __restrict__ x1) {
    __shared__ __align__(16) short cbf[BM * C_];
    __shared__ __align__(16) float xf[BM][132];
    int tid = threadIdx.x;
    int r0 = blockIdx.x * BM;
    {
        int row = tid >> 3;
        int cb = (tid & 7) * 16;
        int gr = r0 + row;
        int t = gr % T_;
        int b = gr / (N_ * T_);
        const float* src = ctx + (size_t)gr * C_ + cb;
        const float* qsrc = query + (size_t)gr * C_ + cb;
        const float* tsrc = tepe + (size_t)(b * T_ + t) * C_ + cb;
#pragma unroll
        for (int i = 0; i < 4; i++) {
            float4 v = *(const float4*)(src + 4 * i);
            short4_ sv;
            sv.x = f2bf(v.x); sv.y = f2bf(v.y); sv.z = f2bf(v.z); sv.w = f2bf(v.w);
            *(short4_*)&cbf[(row * C_ + cb + 4 * i) ^ ((row & 7) << 3)] = sv;
            float4 q4 = *(const float4*)(qsrc + 4 * i);
            float4 t4 = *(const float4*)(tsrc + 4 * i);
            float4 xr;
            xr.x = q4.x + t4.x; xr.y = q4.y + t4.y;
            xr.z = q4.z + t4.z; xr.w = q4.w + t4.w;
            *(float4*)&xf[row][cb + 4 * i] = xr;
        }
    }
    __syncthreads();
    int w = tid >> 6, l = tid & 63;
    int lr = l & 15, lk = l >> 4;
    int rt = w & 1;
    int rrow = rt * 16 + lr;
    short8 bc[4];
#pragma unroll
    for (int ks = 0; ks < 4; ks++)
        bc[ks] = *(const short8*)&cbf[(rrow * C_ + ks * 32 + lk * 8) ^ ((rrow & 7) << 3)];
    int cg = w >> 1;
#pragma unroll
    for (int ct = 0; ct < 4; ct++) {
        int c0t = cg * 64 + ct * 16;
        const short* ap = woT + (size_t)(c0t + lr) * C_;
        f32x4 acc = {0.f, 0.f, 0.f, 0.f};
#pragma unroll
        for (int ks = 0; ks < 4; ks++) {
            short8 af = *(const short8*)(ap + ks * 32 + lk * 8);
            acc = __builtin_amdgcn_mfma_f32_16x16x32_bf16(af, bc[ks], acc, 0, 0, 0);
        }
        int cc = c0t + lk * 4;
        float4 bias = *(const float4*)(bo + cc);
        float4 res = *(const float4*)&xf[rrow][cc];
        float4 o;
        o.x = acc.x + bias.x + res.x;
        o.y = acc.y + bias.y + res.y;
        o.z = acc.z + bias.z + res.z;
        o.w = acc.w + bias.w + res.w;
        *(float4*)&xf[rrow][cc] = o;
    }
    __syncthreads();
    {
        int r = tid >> 3;
        int q = tid & 7;
        int cb = q * 16;
        float vals[16];
        float s = 0.f;
#pragma unroll
        for (int i = 0; i < 16; i++) { vals[i] = xf[r][cb + i]; s += vals[i]; }
        s += __shfl_xor(s, 1, 8);
        s += __shfl_xor(s, 2, 8);
        s += __shfl_xor(s, 4, 8);
        float mean = s * (1.f / C_);
        float vv = 0.f;
#pragma unroll
        for (int i = 0; i < 16; i++) { float d = vals[i] - mean; vv += d * d; }
        vv += __shfl_xor(vv, 1, 8);
        vv += __shfl_xor(vv, 2, 8);
        vv += __shfl_xor(vv, 4, 8);
        float rstd = rsqrtf(vv * (1.f / C_) + 1e-5f);
        float* op = x1 + (size_t)(r0 + r) * C_ + cb;
#pragma unroll
        for (int i4 = 0; i4 < 4; i4++) {
            float4 gv = *(const float4*)(g1 + cb + 4 * i4);
            float4 bv = *(const float4*)(b1 + cb + 4 * i4);
            float4 ov;
            ov.x = (vals[4 * i4 + 0] - mean) * rstd * gv.x + bv.x;
            ov.y = (vals[4 * i4 + 1] - mean) * rstd * gv.y + bv.y;
            ov.z = (vals[4 * i4 + 2] - mean) * rstd * gv.z + bv.z;
            ov.w = (vals[4 * i4 + 3] - mean) * rstd * gv.w + bv.w;
            *(float4*)(op + 4 * i4) = ov;
        }
    }
}

// ---------------- kernel 4: FF via bf16 MFMA + residual + LN2 -> out
__global__ __launch_bounds__(256) void k_ff_mfma(
    const float* __restrict__ x1, const short* __restrict__ w1t, const float* __restrict__ b1f,
    const short* __restrict__ w2t, const float* __restrict__ b2f,
    const float* __restrict__ g2, const float* __restrict__ b2ln,
    float* __restrict__ out) {
    __shared__ __align__(16) short xbf[BM * C_];     // bf16 x, swizzled
    __shared__ __align__(16) float xf[BM][132];      // f32 x (residual), later y
    __shared__ __align__(16) short hbf[BM * FF];     // bf16 hidden, swizzled
    int tid = threadIdx.x;
    int r0 = blockIdx.x * BM;
    {
        int row = tid >> 3;
        int cb = (tid & 7) * 16;
        const float* src = x1 + (size_t)(r0 + row) * C_ + cb;
#pragma unroll
        for (int i = 0; i < 4; i++) {
            float4 v = *(const float4*)(src + 4 * i);
            *(float4*)&xf[row][cb + 4 * i] = v;
            int idx = (row * C_ + cb + 4 * i) ^ ((row & 7) << 3);
            short4_ sv;
            sv.x = f2bf(v.x); sv.y = f2bf(v.y); sv.z = f2bf(v.z); sv.w = f2bf(v.w);
            *(short4_*)&xbf[idx] = sv;
        }
    }
    __syncthreads();
    int w = tid >> 6, l = tid & 63;
    int lr = l & 15, lk = l >> 4;
    int rt = w & 1;
    int rrow = rt * 16 + lr;
    {
        short8 bx[4];
#pragma unroll
        for (int ks = 0; ks < 4; ks++) {
            int k0 = ks * 32 + lk * 8;
            bx[ks] = *(const short8*)&xbf[(rrow * C_ + k0) ^ ((rrow & 7) << 3)];
        }
        int j0base = (w >> 1) * 256;
#pragma unroll 2
        for (int jt = 0; jt < 16; jt++) {
            const short* ap = w1t + (size_t)(j0base + jt * 16 + lr) * C_;
            f32x4 acc = {0.f, 0.f, 0.f, 0.f};
#pragma unroll
            for (int ks = 0; ks < 4; ks++) {
                short8 af = *(const short8*)(ap + ks * 32 + lk * 8);
                acc = __builtin_amdgcn_mfma_f32_16x16x32_bf16(af, bx[ks], acc, 0, 0, 0);
            }
            int j0 = j0base + jt * 16 + lk * 4;
            float4 bias = *(const float4*)(b1f + j0);
            short4_ hv;
            hv.x = f2bf(fmaxf(acc.x + bias.x, 0.f));
            hv.y = f2bf(fmaxf(acc.y + bias.y, 0.f));
            hv.z = f2bf(fmaxf(acc.z + bias.z, 0.f));
            hv.w = f2bf(fmaxf(acc.w + bias.w, 0.f));
            *(short4_*)&hbf[(rrow * FF + j0) ^ ((rrow & 7) << 3)] = hv;
        }
    }
    __syncthreads();
    {
        short8 bh[16];
#pragma unroll
        for (int ks = 0; ks < 16; ks++) {
            int k0 = ks * 32 + lk * 8;
            bh[ks] = *(const short8*)&hbf[(rrow * FF + k0) ^ ((rrow & 7) << 3)];
        }
        int c0base = (w >> 1) * 64;
#pragma unroll
        for (int ct = 0; ct < 4; ct++) {
            const short* ap = w2t + (size_t)(c0base + ct * 16 + lr) * FF;
            f32x4 acc = {0.f, 0.f, 0.f, 0.f};
#pragma unroll
            for (int ks = 0; ks < 16; ks++) {
                short8 af = *(const short8*)(ap + ks * 32 + lk * 8);
                acc = __builtin_amdgcn_mfma_f32_16x16x32_bf16(af, bh[ks], acc, 0, 0, 0);
            }
            int cc = c0base + ct * 16 + lk * 4;
            float4 bias = *(const float4*)(b2f + cc);
            float4 res = *(const float4*)&xf[rrow][cc];
            float4 o;
            o.x = acc.x + bias.x + res.x;
            o.y = acc.y + bias.y + res.y;
            o.z = acc.z + bias.z + res.z;
            o.w = acc.w + bias.w + res.w;
            *(float4*)&xf[rrow][cc] = o;
        }
    }
    __syncthreads();
    {
        int r = tid >> 3;
        int q = tid & 7;
        int cb = q * 16;
        float vals[16];
        float s = 0.f;
#pragma unroll
        for (int i = 0; i < 16; i++) { vals[i] = xf[r][cb + i]; s += vals[i]; }
        s += __shfl_xor(s, 1, 8);
        s += __shfl_xor(s, 2, 8);
        s += __shfl_xor(s, 4, 8);
        float mean = s * (1.f / C_);
        float vv = 0.f;
#pragma unroll
        for (int i = 0; i < 16; i++) { float d = vals[i] - mean; vv += d * d; }
        vv += __shfl_xor(vv, 1, 8);
        vv += __shfl_xor(vv, 2, 8);
        vv += __shfl_xor(vv, 4, 8);
        float rstd = rsqrtf(vv * (1.f / C_) + 1e-5f);
        float* op = out + (size_t)(r0 + r) * C_ + cb;
#pragma unroll
        for (int i4 = 0; i4 < 4; i4++) {
            float4 gv = *(const float4*)(g2 + cb + 4 * i4);
            float4 bv = *(const float4*)(b2ln + cb + 4 * i4);
            float4 ov;
            ov.x = (vals[4 * i4 + 0] - mean) * rstd * gv.x + bv.x;
            ov.y = (vals[4 * i4 + 1] - mean) * rstd * gv.y + bv.y;
            ov.z = (vals[4 * i4 + 2] - mean) * rstd * gv.z + bv.z;
            ov.w = (vals[4 * i4 + 3] - mean) * rstd * gv.w + bv.w;
            *(float4*)(op + 4 * i4) = ov;
        }
    }
}

extern "C" void kernel_launch(void* const* d_in, const int* in_sizes, int n_in,
                              void* d_out, int out_size, void* d_ws, size_t ws_size,
                              hipStream_t stream) {
    const float* query = (const float*)d_in[2];
    const int* time_enc = (const int*)d_in[4];
    const int* index_sample = (const int*)d_in[5];
    const float* e_min = (const float*)d_in[6];
    const float* e_hr  = (const float*)d_in[7];
    const float* e_wd  = (const float*)d_in[8];
    const float* e_mo  = (const float*)d_in[9];
    const float* e_yr  = (const float*)d_in[10];
    const float* Wq = (const float*)d_in[11];
    const float* Wk = (const float*)d_in[12];
    const float* Wv = (const float*)d_in[13];
    const float* Wo = (const float*)d_in[14];
    const float* bo = (const float*)d_in[15];
    const float* ffw1 = (const float*)d_in[16];
    const float* ffb1 = (const float*)d_in[17];
    const float* ffw2 = (const float*)d_in[18];
    const float* ffb2 = (const float*)d_in[19];
    const float* ln1g = (const float*)d_in[20];
    const float* ln1b = (const float*)d_in[21];
    const float* ln2g = (const float*)d_in[22];
    const float* ln2b = (const float*)d_in[23];

    float* ws = (float*)d_ws;
    float* tepe = ws;                 // TEPE_N floats
    float* Qb = ws + TEPE_N;          // NX floats; x1 aliases after attn
    float* Kb = Qb + NX;              // NX floats; w1t/w2t/woT alias after attn
    float* Vb = Kb + NX;              // NX floats
    float* ctxb = Vb + NX;            // NX floats; xbf + wqkvT alias before attn
    float* x1 = Qb;

    short* xbf = (short*)ctxb;                  // NX shorts (first half of ctx region)
    short* wqkvT = (short*)ctxb + NX;           // 49152 shorts (second half; dead before attn)
    short* w1t = (short*)Kb;                    // 65536 shorts (K dead after attn)
    short* w2t = w1t + C_ * FF;                 // 65536 shorts
    short* woT = w2t + C_ * FF;                 // 16384 shorts

    k_tepe<<<dim3(TEPE_N / 256), dim3(256), 0, stream>>>(
        time_enc, e_min, e_hr, e_wd, e_mo, e_yr, tepe);
    k_xprep<<<dim3(NX / 4 / 256), dim3(256), 0, stream>>>(query, tepe, xbf);
    k_wcvt_qkv<<<dim3(384 * C_ / 256), dim3(256), 0, stream>>>(Wq, Wk, Wv, wqkvT);
    k_qkv_mfma<<<dim3(NBLK_MM), dim3(256), 0, stream>>>(xbf, wqkvT, Qb, Kb, Vb);
    k_attn<<<dim3(B_ * H_ * N_), dim3(128), 0, stream>>>(
        Qb, Kb, Vb, index_sample, ctxb);
    k_wcvt2<<<dim3((2 * C_ * FF + C_ * C_) / 256), dim3(256), 0, stream>>>(
        ffw1, ffw2, Wo, w1t, w2t, woT);
    k_out_ln_mfma<<<dim3(NBLK_MM), dim3(256), 0, stream>>>(
        ctxb, woT, bo, query, tepe, ln1g, ln1b, x1);
    k_ff_mfma<<<dim3(NBLK_MM), dim3(256), 0, stream>>>(
        x1, w1t, ffb1, w2t, ffb2, ln2g, ln2b, (float*)d_out);
}